// Round 1
// baseline (2951.670 us; speedup 1.0000x reference)
//
#include <hip/hip_runtime.h>
#include <math.h>

#define N_NODES 585
#define BRANCH 8
#define IN_DIM 512
#define MEM 256
#define IOU_DIM 768
#define BATCH 256

#define BT 64
#define MT 64
#define KT 16

// C[r,m] (+)= sum_k A[r*lda+k] * W[m*ldw+k]   (A @ W.T)
// rows multiple of 64, cols multiple of 64, K multiple of 16 -- all exact here.
__global__ __launch_bounds__(256) void gemm_f32(
    const float* __restrict__ A, int lda,
    const float* __restrict__ W, int ldw,
    float* __restrict__ C, int ldc,
    int K, int accumulate)
{
    __shared__ __align__(16) float As[KT][BT];
    __shared__ __align__(16) float Ws[KT][MT];
    const int r0 = blockIdx.x * BT;
    const int m0 = blockIdx.y * MT;
    const int t  = threadIdx.x;
    const int tx = t % 16, ty = t / 16;
    const int lr = t / 4;         // 0..63
    const int lk = (t % 4) * 4;   // 0,4,8,12
    float acc[4][4] = {};
    for (int k0 = 0; k0 < K; k0 += KT) {
        float4 av = *(const float4*)&A[(size_t)(r0 + lr) * lda + k0 + lk];
        float4 wv = *(const float4*)&W[(size_t)(m0 + lr) * ldw + k0 + lk];
        __syncthreads();
        As[lk+0][lr] = av.x; As[lk+1][lr] = av.y; As[lk+2][lr] = av.z; As[lk+3][lr] = av.w;
        Ws[lk+0][lr] = wv.x; Ws[lk+1][lr] = wv.y; Ws[lk+2][lr] = wv.z; Ws[lk+3][lr] = wv.w;
        __syncthreads();
        #pragma unroll
        for (int kk = 0; kk < KT; ++kk) {
            float4 a4 = *(const float4*)&As[kk][ty * 4];
            float4 w4 = *(const float4*)&Ws[kk][tx * 4];
            float ar[4] = {a4.x, a4.y, a4.z, a4.w};
            float wr[4] = {w4.x, w4.y, w4.z, w4.w};
            #pragma unroll
            for (int i = 0; i < 4; ++i)
                #pragma unroll
                for (int j = 0; j < 4; ++j)
                    acc[i][j] = fmaf(ar[i], wr[j], acc[i][j]);
        }
    }
    #pragma unroll
    for (int i = 0; i < 4; ++i) {
        float* crow = &C[(size_t)(r0 + ty * 4 + i) * ldc + m0 + tx * 4];
        if (accumulate) {
            #pragma unroll
            for (int j = 0; j < 4; ++j) crow[j] += acc[i][j];
        } else {
            #pragma unroll
            for (int j = 0; j < 4; ++j) crow[j] = acc[i][j];
        }
    }
}

// chsum[nl,b,m] = sum_j prob[node,child_j] * h[child_j,b,m];  also zeroes cacc.
__global__ __launch_bounds__(256) void chsum_kernel(
    const float* __restrict__ h_all, const float* __restrict__ prob,
    float* __restrict__ chs, float* __restrict__ cacc, int s)
{
    int idx = blockIdx.x * 256 + threadIdx.x;   // over L*BATCH*MEM
    int m = idx % MEM;
    int b = (idx / MEM) % BATCH;
    int nl = idx / (MEM * BATCH);
    int node = s + nl;
    float acc = 0.f;
    #pragma unroll
    for (int j = 0; j < BRANCH; ++j) {
        int child = node * BRANCH + 1 + j;
        float w = prob[node * N_NODES + child];
        acc += w * h_all[(size_t)child * BATCH * MEM + (size_t)b * MEM + m];
    }
    chs[idx] = acc;
    cacc[idx] = 0.f;
}

// f-gate GEMM: pre = w * (h_child @ Wfh.T) + bfh + bfx + fxbuf; f = sigmoid(pre);
// cacc[nl,b,m] += f * w * c_child[b,m]   (atomic over the 8 children)
__global__ __launch_bounds__(256) void gemm_fgate(
    const float* __restrict__ h_all, const float* __restrict__ c_all,
    const float* __restrict__ prob, const float* __restrict__ Wfh,
    const float* __restrict__ bfh, const float* __restrict__ bfx,
    const float* __restrict__ fxbuf, float* __restrict__ cacc, int s)
{
    const int r0 = blockIdx.x * BT;     // rows: (nl*8 + j)*BATCH + b
    const int m0 = blockIdx.y * MT;
    const int nj = r0 / BATCH;
    const int nl = nj / BRANCH, jc = nj % BRANCH;
    const int b0 = r0 % BATCH;
    const int node = s + nl;
    const int child = node * BRANCH + 1 + jc;
    const float w = prob[node * N_NODES + child];
    const float* A = h_all + (size_t)child * BATCH * MEM;   // lda = MEM

    __shared__ __align__(16) float As[KT][BT];
    __shared__ __align__(16) float Ws[KT][MT];
    const int t  = threadIdx.x;
    const int tx = t % 16, ty = t / 16;
    const int lr = t / 4;
    const int lk = (t % 4) * 4;
    float acc[4][4] = {};
    for (int k0 = 0; k0 < MEM; k0 += KT) {
        float4 av = *(const float4*)&A[(size_t)(b0 + lr) * MEM + k0 + lk];
        float4 wv = *(const float4*)&Wfh[(size_t)(m0 + lr) * MEM + k0 + lk];
        __syncthreads();
        As[lk+0][lr] = av.x; As[lk+1][lr] = av.y; As[lk+2][lr] = av.z; As[lk+3][lr] = av.w;
        Ws[lk+0][lr] = wv.x; Ws[lk+1][lr] = wv.y; Ws[lk+2][lr] = wv.z; Ws[lk+3][lr] = wv.w;
        __syncthreads();
        #pragma unroll
        for (int kk = 0; kk < KT; ++kk) {
            float4 a4 = *(const float4*)&As[kk][ty * 4];
            float4 w4 = *(const float4*)&Ws[kk][tx * 4];
            float ar[4] = {a4.x, a4.y, a4.z, a4.w};
            float wr[4] = {w4.x, w4.y, w4.z, w4.w};
            #pragma unroll
            for (int i = 0; i < 4; ++i)
                #pragma unroll
                for (int j = 0; j < 4; ++j)
                    acc[i][j] = fmaf(ar[i], wr[j], acc[i][j]);
        }
    }
    const float* crow_base = c_all + (size_t)child * BATCH * MEM;
    #pragma unroll
    for (int i = 0; i < 4; ++i) {
        int b = b0 + ty * 4 + i;
        size_t rowoff = ((size_t)nl * BATCH + b) * MEM;
        const float* crow = crow_base + (size_t)b * MEM;
        #pragma unroll
        for (int j = 0; j < 4; ++j) {
            int m = m0 + tx * 4 + j;
            float pre = w * acc[i][j] + bfh[m] + bfx[m] + fxbuf[rowoff + m];
            float f = 1.f / (1.f + expf(-pre));
            atomicAdd(&cacc[rowoff + m], f * (w * crow[m]));
        }
    }
}

// iou (+biases) -> i,o,u -> c,h.  has_children selects cacc contribution.
__global__ __launch_bounds__(256) void pointwise_kernel(
    const float* __restrict__ iou, const float* __restrict__ bioux,
    const float* __restrict__ biouh, const float* __restrict__ cacc,
    float* __restrict__ c_all, float* __restrict__ h_all,
    int node0, int has_children)
{
    int idx = blockIdx.x * 256 + threadIdx.x;   // over Lchunk*BATCH*MEM
    int m = idx % MEM;
    size_t row = (size_t)(idx / MEM);           // nl*BATCH + b
    float ip = iou[row * IOU_DIM + m]           + bioux[m]           + biouh[m];
    float op = iou[row * IOU_DIM + MEM + m]     + bioux[MEM + m]     + biouh[MEM + m];
    float up = iou[row * IOU_DIM + 2*MEM + m]   + bioux[2*MEM + m]   + biouh[2*MEM + m];
    float i = 1.f / (1.f + expf(-ip));
    float o = 1.f / (1.f + expf(-op));
    float u = tanhf(up);
    float c = i * u + (has_children ? cacc[idx] : 0.f);
    float h = o * tanhf(c);
    size_t gidx = (size_t)node0 * BATCH * MEM + idx;
    c_all[gidx] = c;
    h_all[gidx] = h;
}

extern "C" void kernel_launch(void* const* d_in, const int* in_sizes, int n_in,
                              void* d_out, int out_size, void* d_ws, size_t ws_size,
                              hipStream_t stream) {
    const float* inputs = (const float*)d_in[0];
    const float* prob   = (const float*)d_in[1];
    const float* Wioux  = (const float*)d_in[2];
    const float* bioux  = (const float*)d_in[3];
    const float* Wiouh  = (const float*)d_in[4];
    const float* biouh  = (const float*)d_in[5];
    const float* Wfx    = (const float*)d_in[6];
    const float* bfx    = (const float*)d_in[7];
    const float* Wfh    = (const float*)d_in[8];
    const float* bfh    = (const float*)d_in[9];
    float* h_all = (float*)d_out;
    float* ws = (float*)d_ws;

    // workspace layout (floats): total ~63.5M floats = 254 MB
    float* c_all = ws;                                        // 585*256*256
    float* iou   = c_all + (size_t)N_NODES * BATCH * MEM;     // 64*256*768
    float* fx    = iou   + (size_t)64 * BATCH * IOU_DIM;      // 64*256*256
    float* chs   = fx    + (size_t)64 * BATCH * MEM;          // 64*256*256
    float* cacc  = chs   + (size_t)64 * BATCH * MEM;          // 64*256*256

    dim3 blk(256);

    // ---- leaves (nodes 73..584), 8 chunks of 64 nodes ----
    for (int chunk = 0; chunk < 8; ++chunk) {
        int node0 = 73 + chunk * 64;
        const float* A = inputs + (size_t)node0 * BATCH * IN_DIM;
        int rows = 64 * BATCH;
        gemm_f32<<<dim3(rows / BT, IOU_DIM / MT), blk, 0, stream>>>(
            A, IN_DIM, Wioux, IN_DIM, iou, IOU_DIM, IN_DIM, 0);
        pointwise_kernel<<<dim3(rows * MEM / 256), blk, 0, stream>>>(
            iou, bioux, biouh, cacc, c_all, h_all, node0, 0);
    }

    // ---- upper levels: 64 nodes @9, 8 nodes @1, 1 node @0 ----
    const int starts[3] = {9, 1, 0};
    const int sizes_[3] = {64, 8, 1};
    for (int li = 0; li < 3; ++li) {
        int s = starts[li], L = sizes_[li];
        int rows = L * BATCH;
        const float* A = inputs + (size_t)s * BATCH * IN_DIM;
        gemm_f32<<<dim3(rows / BT, IOU_DIM / MT), blk, 0, stream>>>(
            A, IN_DIM, Wioux, IN_DIM, iou, IOU_DIM, IN_DIM, 0);
        gemm_f32<<<dim3(rows / BT, MEM / MT), blk, 0, stream>>>(
            A, IN_DIM, Wfx, IN_DIM, fx, MEM, IN_DIM, 0);
        chsum_kernel<<<dim3(rows * MEM / 256), blk, 0, stream>>>(
            h_all, prob, chs, cacc, s);
        gemm_f32<<<dim3(rows / BT, IOU_DIM / MT), blk, 0, stream>>>(
            chs, MEM, Wiouh, MEM, iou, IOU_DIM, MEM, 1);
        gemm_fgate<<<dim3(L * BRANCH * BATCH / BT, MEM / MT), blk, 0, stream>>>(
            h_all, c_all, prob, Wfh, bfh, bfx, fx, cacc, s);
        pointwise_kernel<<<dim3(rows * MEM / 256), blk, 0, stream>>>(
            iou, bioux, biouh, cacc, c_all, h_all, s, 1);
    }
}

// Round 2
// 1135.046 us; speedup vs baseline: 2.6005x; 2.6005x over previous
//
#include <hip/hip_runtime.h>
#include <math.h>

typedef _Float16 h8_t __attribute__((ext_vector_type(8)));
typedef _Float16 h4_t __attribute__((ext_vector_type(4)));
typedef float f4_t __attribute__((ext_vector_type(4)));

#define LDSW 40   // 32 k + 8 pad, in halfs

// stage 64 rows x 32 k from fp32 source into LDS (cvt to f16)
__device__ __forceinline__ void stage_f32(const float* __restrict__ src, int ld,
                                          _Float16* __restrict__ dst, int t) {
#pragma unroll
  for (int it = 0; it < 2; ++it) {
    int idx = t + it * 256;       // 0..511
    int row = idx >> 3;           // 0..63
    int kg  = (idx & 7) << 2;     // 0,4,..,28
    float4 v = *(const float4*)(src + (size_t)row * ld + kg);
    h4_t h = {(_Float16)v.x, (_Float16)v.y, (_Float16)v.z, (_Float16)v.w};
    *(h4_t*)(dst + row * LDSW + kg) = h;
  }
}

// stage 64 rows x 32 k from f16 source into LDS
__device__ __forceinline__ void stage_f16(const _Float16* __restrict__ src, int ld,
                                          _Float16* __restrict__ dst, int t) {
  int row = t >> 2;               // 0..63
  int kg  = (t & 3) << 3;         // 0,8,16,24
  *(h8_t*)(dst + row * LDSW + kg) = *(const h8_t*)(src + (size_t)row * ld + kg);
}

// Convert the 4 weight matrices fp32 -> f16 (one launch)
__global__ __launch_bounds__(256) void convert_weights(
    const float* __restrict__ Wioux, const float* __restrict__ Wiouh,
    const float* __restrict__ Wfx, const float* __restrict__ Wfh,
    _Float16* __restrict__ Wx, _Float16* __restrict__ Wh,
    _Float16* __restrict__ Wfxh, _Float16* __restrict__ Wfhh)
{
  int i4 = (blockIdx.x * 256 + threadIdx.x) * 4;   // < 786432
  const float* src; _Float16* dst; int off;
  if (i4 < 393216)      { src = Wioux; dst = Wx;   off = i4; }
  else if (i4 < 589824) { src = Wiouh; dst = Wh;   off = i4 - 393216; }
  else if (i4 < 720896) { src = Wfx;   dst = Wfxh; off = i4 - 589824; }
  else                  { src = Wfh;   dst = Wfhh; off = i4 - 720896; }
  float4 v = *(const float4*)(src + off);
  h4_t h = {(_Float16)v.x, (_Float16)v.y, (_Float16)v.z, (_Float16)v.w};
  *(h4_t*)(dst + off) = h;
}

// fx = x @ Wfx.T  for nodes 0..72 (rows = 73*256), fp32 out, no bias
__global__ __launch_bounds__(256) void fx_gemm(
    const float* __restrict__ x, const _Float16* __restrict__ Wfx,
    float* __restrict__ out)
{
  __shared__ _Float16 As[64 * LDSW];
  __shared__ _Float16 Bs[64 * LDSW];
  const int t = threadIdx.x;
  const int m0 = blockIdx.x * 64;
  const int r0 = blockIdx.y * 64;
  const int w = t >> 6, lane = t & 63;
  const int wr = (w >> 1) * 32, wc = (w & 1) * 32;
  const int fr = lane & 15, fq = (lane >> 4) * 8;
  f4_t acc[2][2] = {};
  for (int k0 = 0; k0 < 512; k0 += 32) {
    __syncthreads();
    stage_f32(x + (size_t)r0 * 512 + k0, 512, As, t);
    stage_f16(Wfx + (size_t)m0 * 512 + k0, 512, Bs, t);
    __syncthreads();
    h8_t a[2], b[2];
#pragma unroll
    for (int rt = 0; rt < 2; ++rt)
      a[rt] = *(const h8_t*)(As + (wr + rt * 16 + fr) * LDSW + fq);
#pragma unroll
    for (int ct = 0; ct < 2; ++ct)
      b[ct] = *(const h8_t*)(Bs + (wc + ct * 16 + fr) * LDSW + fq);
#pragma unroll
    for (int rt = 0; rt < 2; ++rt)
#pragma unroll
      for (int ct = 0; ct < 2; ++ct)
        acc[rt][ct] = __builtin_amdgcn_mfma_f32_16x16x32_f16(a[rt], b[ct], acc[rt][ct], 0, 0, 0);
  }
#pragma unroll
  for (int rt = 0; rt < 2; ++rt)
#pragma unroll
    for (int ct = 0; ct < 2; ++ct)
#pragma unroll
      for (int i = 0; i < 4; ++i) {
        int row = wr + rt * 16 + (lane >> 4) * 4 + i;
        int col = wc + ct * 16 + (lane & 15);
        out[(size_t)(r0 + row) * 256 + m0 + col] = acc[rt][ct][i];
      }
}

// chs[nl,b,m] = f16( sum_j w_j * h[child_j,b,m] )
__global__ __launch_bounds__(256) void chs_kernel(
    const float* __restrict__ h_all, const float* __restrict__ prob,
    _Float16* __restrict__ chs, int s)
{
  int idx = blockIdx.x * 256 + threadIdx.x;   // over L*16384
  int m = (idx & 63) << 2;
  int b = (idx >> 6) & 255;
  int nl = idx >> 14;
  int node = s + nl;
  float4 acc = {0.f, 0.f, 0.f, 0.f};
#pragma unroll
  for (int j = 0; j < 8; ++j) {
    int child = node * 8 + 1 + j;
    float wv = prob[node * 585 + child];
    float4 hv = *(const float4*)(h_all + (size_t)child * 65536 + b * 256 + m);
    acc.x += wv * hv.x; acc.y += wv * hv.y; acc.z += wv * hv.z; acc.w += wv * hv.w;
  }
  h4_t hc = {(_Float16)acc.x, (_Float16)acc.y, (_Float16)acc.z, (_Float16)acc.w};
  *(h4_t*)(chs + (size_t)nl * 65536 + b * 256 + m) = hc;
}

// Per (node, b-tile, m-tile): loop 8 children; GEMM h_child@Wfh.T; epilogue
// accumulates sigmoid(w*acc + bfh + bfx + fx) * w * c_child. No atomics.
__global__ __launch_bounds__(256) void fgate_kernel(
    const _Float16* __restrict__ h_half, const _Float16* __restrict__ c_half,
    const float* __restrict__ prob, const _Float16* __restrict__ Wfh,
    const float* __restrict__ bfh, const float* __restrict__ bfx,
    const float* __restrict__ fxb, float* __restrict__ cacc, int s)
{
  __shared__ _Float16 As[64 * LDSW];
  __shared__ _Float16 Bs[64 * 264];   // full 64 x 256 Wfh tile, pad 8
  const int t = threadIdx.x;
  const int m0 = blockIdx.x * 64;
  const int nl = blockIdx.y >> 2;
  const int b0 = (blockIdx.y & 3) * 64;
  const int node = s + nl;
  const int w = t >> 6, lane = t & 63;
  const int wr = (w >> 1) * 32, wc = (w & 1) * 32;
  const int fr = lane & 15, fq = (lane >> 4) * 8;

#pragma unroll
  for (int it = 0; it < 8; ++it) {
    int idx = t + it * 256;           // 0..2047
    int row = idx >> 5;               // 0..63
    int kg  = (idx & 31) << 3;        // 0..248
    *(h8_t*)(Bs + row * 264 + kg) = *(const h8_t*)(Wfh + (size_t)(m0 + row) * 256 + kg);
  }
  float basep[2][2][4];
#pragma unroll
  for (int rt = 0; rt < 2; ++rt)
#pragma unroll
    for (int ct = 0; ct < 2; ++ct)
#pragma unroll
      for (int i = 0; i < 4; ++i) {
        int row = wr + rt * 16 + (lane >> 4) * 4 + i;
        int col = wc + ct * 16 + (lane & 15);
        int m = m0 + col;
        basep[rt][ct][i] = bfh[m] + bfx[m] + fxb[((size_t)node * 256 + b0 + row) * 256 + m];
      }
  f4_t fc[2][2] = {};
  for (int j = 0; j < 8; ++j) {
    int child = node * 8 + 1 + j;
    float wj = prob[node * 585 + child];
    const _Float16* Ab = h_half + (size_t)child * 65536 + (size_t)b0 * 256;
    f4_t acc[2][2] = {};
    for (int k0 = 0; k0 < 256; k0 += 32) {
      __syncthreads();
      stage_f16(Ab + k0, 256, As, t);
      __syncthreads();
      h8_t a[2], b[2];
#pragma unroll
      for (int rt = 0; rt < 2; ++rt)
        a[rt] = *(const h8_t*)(As + (wr + rt * 16 + fr) * LDSW + fq);
#pragma unroll
      for (int ct = 0; ct < 2; ++ct)
        b[ct] = *(const h8_t*)(Bs + (wc + ct * 16 + fr) * 264 + k0 + fq);
#pragma unroll
      for (int rt = 0; rt < 2; ++rt)
#pragma unroll
        for (int ct = 0; ct < 2; ++ct)
          acc[rt][ct] = __builtin_amdgcn_mfma_f32_16x16x32_f16(a[rt], b[ct], acc[rt][ct], 0, 0, 0);
    }
    const _Float16* cb = c_half + (size_t)child * 65536 + (size_t)b0 * 256;
#pragma unroll
    for (int rt = 0; rt < 2; ++rt)
#pragma unroll
      for (int ct = 0; ct < 2; ++ct)
#pragma unroll
        for (int i = 0; i < 4; ++i) {
          int row = wr + rt * 16 + (lane >> 4) * 4 + i;
          int col = wc + ct * 16 + (lane & 15);
          float pre = wj * acc[rt][ct][i] + basep[rt][ct][i];
          float f = 1.f / (1.f + expf(-pre));
          fc[rt][ct][i] += f * wj * (float)cb[row * 256 + m0 + col];
        }
  }
#pragma unroll
  for (int rt = 0; rt < 2; ++rt)
#pragma unroll
    for (int ct = 0; ct < 2; ++ct)
#pragma unroll
      for (int i = 0; i < 4; ++i) {
        int row = wr + rt * 16 + (lane >> 4) * 4 + i;
        int col = wc + ct * 16 + (lane & 15);
        cacc[((size_t)nl * 256 + b0 + row) * 256 + m0 + col] = fc[rt][ct][i];
      }
}

// Fused iou GEMM + pointwise. Block owns 64 rows x 64 m-cols across ALL 3
// gates (i at m, o at 256+m, u at 512+m). Phase 0: K=512 from x (fp32->f16
// on the fly); phase 1 (internal only): K=256 from chs (f16).
// Epilogue: c = sig(i)*tanh(u) + cacc, h = sig(o)*tanh(c); writes h_all(f32),
// h_half(f16), c_half(f16).
__global__ __launch_bounds__(256) void iou_fused(
    const float* __restrict__ x, const _Float16* __restrict__ chs,
    const float* __restrict__ cacc,
    const _Float16* __restrict__ Wx, const _Float16* __restrict__ Wh,
    const float* __restrict__ bioux, const float* __restrict__ biouh,
    _Float16* __restrict__ c_half, _Float16* __restrict__ h_half,
    float* __restrict__ h_all, int node0)
{
  __shared__ _Float16 As[64 * LDSW];
  __shared__ _Float16 Bs[3][64 * LDSW];
  const int t = threadIdx.x;
  const int m0 = blockIdx.x * 64;
  const int r0 = blockIdx.y * 64;
  const int w = t >> 6, lane = t & 63;
  const int wr = (w >> 1) * 32, wc = (w & 1) * 32;
  const int fr = lane & 15, fq = (lane >> 4) * 8;

  f4_t acc[3][2][2] = {};
  for (int ph = 0; ph < 2; ++ph) {
    if (ph == 1 && chs == nullptr) break;
    const int K = ph ? 256 : 512;
    const _Float16* W = ph ? Wh : Wx;
    for (int k0 = 0; k0 < K; k0 += 32) {
      __syncthreads();
      if (ph == 0) stage_f32(x + (size_t)r0 * 512 + k0, 512, As, t);
      else         stage_f16(chs + (size_t)r0 * 256 + k0, 256, As, t);
#pragma unroll
      for (int g = 0; g < 3; ++g)
        stage_f16(W + (size_t)(g * 256 + m0) * K + k0, K, &Bs[g][0], t);
      __syncthreads();
      h8_t a[2], b[3][2];
#pragma unroll
      for (int rt = 0; rt < 2; ++rt)
        a[rt] = *(const h8_t*)(As + (wr + rt * 16 + fr) * LDSW + fq);
#pragma unroll
      for (int g = 0; g < 3; ++g)
#pragma unroll
        for (int ct = 0; ct < 2; ++ct)
          b[g][ct] = *(const h8_t*)(&Bs[g][0] + (wc + ct * 16 + fr) * LDSW + fq);
#pragma unroll
      for (int g = 0; g < 3; ++g)
#pragma unroll
        for (int rt = 0; rt < 2; ++rt)
#pragma unroll
          for (int ct = 0; ct < 2; ++ct)
            acc[g][rt][ct] = __builtin_amdgcn_mfma_f32_16x16x32_f16(a[rt], b[g][ct], acc[g][rt][ct], 0, 0, 0);
    }
  }
#pragma unroll
  for (int rt = 0; rt < 2; ++rt)
#pragma unroll
    for (int ct = 0; ct < 2; ++ct)
#pragma unroll
      for (int i = 0; i < 4; ++i) {
        int row = wr + rt * 16 + (lane >> 4) * 4 + i;
        int col = wc + ct * 16 + (lane & 15);
        int m = m0 + col;
        size_t lrow = (size_t)(r0 + row);
        float iv = acc[0][rt][ct][i] + bioux[m] + biouh[m];
        float ov = acc[1][rt][ct][i] + bioux[256 + m] + biouh[256 + m];
        float uv = acc[2][rt][ct][i] + bioux[512 + m] + biouh[512 + m];
        float ig = 1.f / (1.f + expf(-iv));
        float og = 1.f / (1.f + expf(-ov));
        float ug = tanhf(uv);
        float c = ig * ug + (cacc ? cacc[lrow * 256 + m] : 0.f);
        float h = og * tanhf(c);
        size_t g = ((size_t)node0 * 256 + lrow) * 256 + m;
        h_all[g] = h;
        h_half[g] = (_Float16)h;
        c_half[g] = (_Float16)c;
      }
}

extern "C" void kernel_launch(void* const* d_in, const int* in_sizes, int n_in,
                              void* d_out, int out_size, void* d_ws, size_t ws_size,
                              hipStream_t stream) {
  const float* inputs = (const float*)d_in[0];
  const float* prob   = (const float*)d_in[1];
  const float* Wioux  = (const float*)d_in[2];
  const float* bioux  = (const float*)d_in[3];
  const float* Wiouh  = (const float*)d_in[4];
  const float* biouh  = (const float*)d_in[5];
  const float* Wfx    = (const float*)d_in[6];
  const float* bfx    = (const float*)d_in[7];
  const float* Wfh    = (const float*)d_in[8];
  const float* bfh    = (const float*)d_in[9];
  float* h_out = (float*)d_out;

  char* p = (char*)d_ws;
  _Float16* c_half = (_Float16*)p; p += (size_t)585 * 65536 * 2;
  _Float16* h_half = (_Float16*)p; p += (size_t)585 * 65536 * 2;
  float*    fxb    = (float*)p;    p += (size_t)73 * 65536 * 4;
  _Float16* chs    = (_Float16*)p; p += (size_t)64 * 65536 * 2;
  float*    cacc   = (float*)p;    p += (size_t)64 * 65536 * 4;
  _Float16* Wx     = (_Float16*)p; p += (size_t)393216 * 2;
  _Float16* Wh     = (_Float16*)p; p += (size_t)196608 * 2;
  _Float16* Wfxh   = (_Float16*)p; p += (size_t)131072 * 2;
  _Float16* Wfhh   = (_Float16*)p; p += (size_t)65536 * 2;

  convert_weights<<<768, 256, 0, stream>>>(Wioux, Wiouh, Wfx, Wfh, Wx, Wh, Wfxh, Wfhh);
  fx_gemm<<<dim3(4, 292), 256, 0, stream>>>(inputs, Wfxh, fxb);

  // leaves: nodes 73..584, rows = 512*256
  iou_fused<<<dim3(4, 2048), 256, 0, stream>>>(
      inputs + (size_t)73 * 131072, nullptr, nullptr,
      Wx, Wh, bioux, biouh, c_half, h_half, h_out, 73);

  const int starts[3] = {9, 1, 0};
  const int sizes_[3] = {64, 8, 1};
  for (int li = 0; li < 3; ++li) {
    int s = starts[li], L = sizes_[li];
    chs_kernel<<<L * 64, 256, 0, stream>>>(h_out, prob, chs, s);
    fgate_kernel<<<dim3(4, L * 4), 256, 0, stream>>>(
        h_half, c_half, prob, Wfhh, bfh, bfx, fxb, cacc, s);
    iou_fused<<<dim3(4, L * 4), 256, 0, stream>>>(
        inputs + (size_t)s * 131072, chs, cacc,
        Wx, Wh, bioux, biouh, c_half, h_half, h_out, s);
  }
}